// Round 22
// baseline (653.221 us; speedup 1.0000x reference)
//
#include <hip/hip_runtime.h>
#include <math.h>

typedef long long i64;
typedef short short8v __attribute__((ext_vector_type(8)));
typedef float float4v __attribute__((ext_vector_type(4)));

#define Hd 256
#define Bb 64
#define Tn 2047
#define LEAF0 1023
#define NTH 33538048LL   // B*T*H elements

__device__ __forceinline__ float frcp(float x){ return __builtin_amdgcn_rcpf(x); }
__device__ __forceinline__ float sigm(float x){ return frcp(1.0f+__expf(-x)); }
__device__ __forceinline__ float ftanh(float x){ return 1.0f - 2.0f*frcp(__expf(2.0f*x)+1.0f); }
__device__ __forceinline__ float bf2f(unsigned short s){
  union { unsigned u; float f; } v; v.u = ((unsigned)s)<<16; return v.f; }
__device__ __forceinline__ short f2bf(float f){
  union { float f; unsigned u; } v; v.f = f;
  unsigned r = v.u + 0x7FFF + ((v.u>>16)&1);
  return (short)(r>>16); }

#define GL2LDS(gp, lp) __builtin_amdgcn_global_load_lds( \
  (const __attribute__((address_space(1))) void*)(gp), \
  (__attribute__((address_space(3))) void*)(lp), 16, 0, 0)

// ---------------------------------------------------------------------------
// prep (R21 verbatim)
// ---------------------------------------------------------------------------
__global__ __launch_bounds__(256)
void prep_kernel(const float* __restrict__ W_iou, const float* __restrict__ U_iou,
                 const float* __restrict__ U_f_w,
                 short* __restrict__ Wt2I, short* __restrict__ Wt2L,
                 const int* __restrict__ wordid, const float* __restrict__ emb,
                 short* __restrict__ hb, short* __restrict__ cbb){
  if (blockIdx.x < 320){
    int t = blockIdx.x*256 + threadIdx.x;
    int lane = t & 63, rest = t >> 6;
    int nr = rest % 20; int rest2 = rest / 20;
    int kt = rest2 & 15, hhb = rest2 >> 4;
    int g = nr/5, strip = nr - g*5;
    int j = strip*256 + hhb*64 + g*16 + (lane&15);
    int k0 = kt*32 + (lane>>4)*8;
    const float* src = (j < 768) ? (U_iou + (i64)j*512 + k0)
                                 : (U_f_w + (i64)(j-768)*512 + k0);
    short* dst = Wt2I + (i64)t*8;
    #pragma unroll
    for (int e=0;e<8;e++) dst[e] = f2bf(src[e]);
  } else if (blockIdx.x < 416){
    int t2 = (blockIdx.x-320)*256 + threadIdx.x;
    int lane = t2 & 63, rest = t2 >> 6;
    int nr = rest % 12; int rest2 = rest / 12;
    int kt = rest2 & 7, hhb = rest2 >> 3;
    int g = nr/3, strip = nr - g*3;
    int j = strip*256 + hhb*64 + g*16 + (lane&15);
    int k0 = kt*32 + (lane>>4)*8;
    const float* src = W_iou + (i64)j*256 + k0;
    short* dst = Wt2L + (i64)t2*8;
    #pragma unroll
    for (int e=0;e<8;e++) dst[e] = f2bf(src[e]);
  } else {
    int id = (blockIdx.x-416)*256 + threadIdx.x;
    int row = id >> 5, q = id & 31;
    int b = row >> 10, j = row & 1023;
    i64 tb = (i64)b*Tn;
    const int* wid = wordid + (tb + LEAF0 + j)*5;
    float s[8];
    #pragma unroll
    for (int e=0;e<8;e++) s[e] = 0.f;
    #pragma unroll
    for (int l=0;l<5;l++){
      const float* er = emb + (i64)wid[l]*Hd + q*8;
      float4 v0 = *(const float4*)(er);
      float4 v1 = *(const float4*)(er+4);
      s[0]+=v0.x; s[1]+=v0.y; s[2]+=v0.z; s[3]+=v0.w;
      s[4]+=v1.x; s[5]+=v1.y; s[6]+=v1.z; s[7]+=v1.w;
    }
    short o[8];
    #pragma unroll
    for (int e=0;e<8;e++) o[e] = f2bf(s[e]);
    short* dst = (j < 1023) ? (hb + (tb + j)*Hd) : (cbb + tb*Hd);
    *(short8v*)(dst + q*8) = *(short8v*)o;
  }
}

// ---------------------------------------------------------------------------
// Leaf GEMM (R21 verbatim, no c0 read): BK=64, 4 iters, 1 barrier/iter.
// ---------------------------------------------------------------------------
#define LEAF_IT(I, V1, V2)                                                   \
  {                                                                          \
    _Pragma("unroll")                                                        \
    for (int st=0; st<3; ++st)                                               \
      qb[st] = *(const short8v*)(wbB + (i64)((I)*2+1)*12*512 + (i64)st*512); \
    asm volatile("" ::: "memory");                                           \
    if ((I)+2 < 4) GL2LDS(srcA + ((I)+2)*64, &As[(((I)+2)&3)*4096 + w*512]); \
    asm volatile("" ::: "memory");                                           \
    asm volatile("s_waitcnt vmcnt(" #V1 ")" ::: "memory");                   \
    __builtin_amdgcn_s_barrier();                                            \
    asm volatile("" ::: "memory");                                           \
    {                                                                        \
      short8v a0 = *(const short8v*)&As[((I)&3)*4096 + (wm*2+0)*512 + lane*8]; \
      short8v a1 = *(const short8v*)&As[((I)&3)*4096 + (wm*2+1)*512 + lane*8]; \
      _Pragma("unroll")                                                      \
      for (int st=0; st<3; ++st){                                            \
        acc[0][st] = __builtin_amdgcn_mfma_f32_16x16x32_bf16(a0, pb[st], acc[0][st], 0,0,0); \
        acc[1][st] = __builtin_amdgcn_mfma_f32_16x16x32_bf16(a1, pb[st], acc[1][st], 0,0,0); \
      }                                                                      \
    }                                                                        \
    asm volatile("" ::: "memory");                                           \
    if ((I)+1 < 4){                                                          \
      _Pragma("unroll")                                                      \
      for (int st=0; st<3; ++st)                                             \
        pb[st] = *(const short8v*)(wbB + (i64)((I)+1)*2*12*512 + (i64)st*512); \
    }                                                                        \
    asm volatile("" ::: "memory");                                           \
    asm volatile("s_waitcnt vmcnt(" #V2 ")" ::: "memory");                   \
    {                                                                        \
      short8v a0 = *(const short8v*)&As[((I)&3)*4096 + 2048 + (wm*2+0)*512 + lane*8]; \
      short8v a1 = *(const short8v*)&As[((I)&3)*4096 + 2048 + (wm*2+1)*512 + lane*8]; \
      _Pragma("unroll")                                                      \
      for (int st=0; st<3; ++st){                                            \
        acc[0][st] = __builtin_amdgcn_mfma_f32_16x16x32_bf16(a0, qb[st], acc[0][st], 0,0,0); \
        acc[1][st] = __builtin_amdgcn_mfma_f32_16x16x32_bf16(a1, qb[st], acc[1][st], 0,0,0); \
      }                                                                      \
    }                                                                        \
    asm volatile("s_waitcnt lgkmcnt(0)" ::: "memory");                       \
  }

__global__ __launch_bounds__(512, 4)
void leaf_gemm(const short* __restrict__ hb, const short* __restrict__ cbb,
               const short* __restrict__ WB,
               const float* __restrict__ b_iou,
               float* __restrict__ hOut, short* __restrict__ hbOut,
               short* __restrict__ cbbOut){
  __shared__ __align__(16) short As[4*4096];   // 32 KB ring-4
  const int tid = threadIdx.x;
  const int lane = tid & 63, w = tid >> 6;
  const int wm = w >> 2, wg = w & 3;           // output role
  const int bid = blockIdx.x;
  const int hhb = bid & 3;
  const int m0 = (bid >> 2) * 64;

  const short* srcA;                            // staging role: rg=w&3, sub=w>>2
  {
    const int r = m0 + (w&3)*16 + (lane&15);
    const int bA = r >> 10, jA = r & 1023;
    srcA = ((jA < 1023) ? (hb + ((i64)bA*Tn + jA)*Hd) : (cbb + (i64)bA*Tn*Hd))
           + (w>>2)*32 + (lane>>4)*8;
  }
  const short* wbB = WB + (i64)hhb*96*512 + (i64)(wg*3)*512 + lane*8;

  float4v acc[2][3];
  #pragma unroll
  for (int mr=0;mr<2;mr++)
    #pragma unroll
    for (int st=0;st<3;st++){ float4v z = {0.f,0.f,0.f,0.f}; acc[mr][st] = z; }

  short8v pb[3], qb[3];
  #pragma unroll
  for (int st=0; st<3; ++st) pb[st] = *(const short8v*)(wbB + (i64)st*512);
  asm volatile("" ::: "memory");
  GL2LDS(srcA,      &As[0*4096 + w*512]);
  GL2LDS(srcA + 64, &As[1*4096 + w*512]);
  asm volatile("" ::: "memory");

  LEAF_IT(0,5,4)  LEAF_IT(1,4,4)  LEAF_IT(2,3,3)  LEAF_IT(3,3,0)

  const int hcol = hhb*64 + wg*16 + (lane&15);
  const float bi = b_iou[hcol], bo = b_iou[256+hcol], bu = b_iou[512+hcol];
  #pragma unroll
  for (int mr=0;mr<2;mr++){
    const int mgb = m0 + wm*32 + mr*16 + ((lane>>4)<<2);
    #pragma unroll
    for (int r=0;r<4;r++){
      const int m = mgb + r;
      const int b = m >> 10, j = m & 1023;
      const i64 n = (i64)b*Tn + LEAF0 + j;
      const float i_ = acc[mr][0][r] + bi;
      const float o_ = acc[mr][1][r] + bo;
      const float u_ = acc[mr][2][r] + bu;
      const float cn = sigm(i_)*ftanh(u_);            // c0 == 0 for this problem
      const float hv = sigm(o_)*ftanh(cn);
      cbbOut[n*Hd + hcol] = f2bf(cn);
      hbOut[n*Hd + hcol]  = f2bf(hv);
      hOut[n*Hd + hcol] = hv;
    }
  }
}

// ---------------------------------------------------------------------------
// Internal level d=9..6 (R21 verbatim)
// ---------------------------------------------------------------------------
#define LVL_IT(I, V1, V2)                                                    \
  {                                                                          \
    _Pragma("unroll")                                                        \
    for (int st=0; st<5; ++st)                                               \
      qb[st] = *(const short8v*)(wbB + (i64)((I)*2+1)*20*512 + (i64)st*512); \
    asm volatile("" ::: "memory");                                           \
    if ((I)+2 < 8) GL2LDS(srcA + ((I)+2)*64, &As[(((I)+2)&3)*4096 + w*512]); \
    asm volatile("" ::: "memory");                                           \
    asm volatile("s_waitcnt vmcnt(" #V1 ")" ::: "memory");                   \
    __builtin_amdgcn_s_barrier();                                            \
    asm volatile("" ::: "memory");                                           \
    {                                                                        \
      short8v a0 = *(const short8v*)&As[((I)&3)*4096 + (wm*2+0)*512 + lane*8]; \
      short8v a1 = *(const short8v*)&As[((I)&3)*4096 + (wm*2+1)*512 + lane*8]; \
      _Pragma("unroll")                                                      \
      for (int st=0; st<5; ++st){                                            \
        acc[0][st] = __builtin_amdgcn_mfma_f32_16x16x32_bf16(a0, pb[st], acc[0][st], 0,0,0); \
        acc[1][st] = __builtin_amdgcn_mfma_f32_16x16x32_bf16(a1, pb[st], acc[1][st], 0,0,0); \
      }                                                                      \
    }                                                                        \
    asm volatile("" ::: "memory");                                           \
    if ((I)+1 < 8){                                                          \
      _Pragma("unroll")                                                      \
      for (int st=0; st<5; ++st)                                             \
        pb[st] = *(const short8v*)(wbB + (i64)((I)+1)*2*20*512 + (i64)st*512); \
    }                                                                        \
    asm volatile("" ::: "memory");                                           \
    asm volatile("s_waitcnt vmcnt(" #V2 ")" ::: "memory");                   \
    {                                                                        \
      short8v a0 = *(const short8v*)&As[((I)&3)*4096 + 2048 + (wm*2+0)*512 + lane*8]; \
      short8v a1 = *(const short8v*)&As[((I)&3)*4096 + 2048 + (wm*2+1)*512 + lane*8]; \
      _Pragma("unroll")                                                      \
      for (int st=0; st<5; ++st){                                            \
        acc[0][st] = __builtin_amdgcn_mfma_f32_16x16x32_bf16(a0, qb[st], acc[0][st], 0,0,0); \
        acc[1][st] = __builtin_amdgcn_mfma_f32_16x16x32_bf16(a1, qb[st], acc[1][st], 0,0,0); \
      }                                                                      \
    }                                                                        \
    asm volatile("s_waitcnt lgkmcnt(0)" ::: "memory");                       \
  }

__global__ __launch_bounds__(512, 4)
void level_gemm(const short* __restrict__ WB,
                const float* __restrict__ b_iou, const float* __restrict__ U_f_b,
                float* __restrict__ hOut, short* __restrict__ hb, short* __restrict__ cbb,
                int s0, int e0, int logn){
  __shared__ __align__(16) short As[4*4096];   // 32 KB ring-4
  const int tid = threadIdx.x;
  const int lane = tid & 63, w = tid >> 6;
  const int wm = w >> 2, wg = w & 3;
  const int bid = blockIdx.x;
  const int hhb = bid & 3;
  const int m0 = (bid >> 2) * 64;
  const int nm1 = (1<<logn)-1;

  const short* srcA;
  {
    const int r = m0 + (w&3)*16 + (lane&15);
    const int bA = r >> logn, jA = r & nm1;
    srcA = hb + ((i64)bA*Tn + e0)*Hd + (i64)jA*512 + (w>>2)*32 + (lane>>4)*8;
  }
  const short* wbB = WB + (i64)hhb*320*512 + (i64)(wg*5)*512 + lane*8;

  float4v acc[2][5];
  #pragma unroll
  for (int mr=0;mr<2;mr++)
    #pragma unroll
    for (int st=0;st<5;st++){ float4v z = {0.f,0.f,0.f,0.f}; acc[mr][st] = z; }

  short8v pb[5], qb[5];
  #pragma unroll
  for (int st=0; st<5; ++st) pb[st] = *(const short8v*)(wbB + (i64)st*512);
  asm volatile("" ::: "memory");
  GL2LDS(srcA,      &As[0*4096 + w*512]);
  GL2LDS(srcA + 64, &As[1*4096 + w*512]);
  asm volatile("" ::: "memory");

  LVL_IT(0,7,6)  LVL_IT(1,6,6)  LVL_IT(2,6,6)  LVL_IT(3,6,6)
  LVL_IT(4,6,6)  LVL_IT(5,6,6)  LVL_IT(6,5,5)  LVL_IT(7,5,0)

  const int hcol = hhb*64 + wg*16 + (lane&15);
  const float bi = b_iou[hcol], bo = b_iou[256+hcol], bu = b_iou[512+hcol];
  const float bfl = U_f_b[hcol], bfr2 = U_f_b[256+hcol];
  #pragma unroll
  for (int mr=0;mr<2;mr++){
    const int mgb = m0 + wm*32 + mr*16 + ((lane>>4)<<2);
    #pragma unroll
    for (int r=0;r<4;r++){
      const int m = mgb + r;
      const int b = m >> logn, j = m & nm1;
      const i64 base = (i64)b*Tn;
      const i64 cidx = (base + e0 + 2*j)*Hd + hcol;
      const float cl = bf2f((unsigned short)cbb[cidx]);
      const float cr = bf2f((unsigned short)cbb[cidx + Hd]);
      const float i_ = acc[mr][0][r]+bi, o_ = acc[mr][1][r]+bo, u_ = acc[mr][2][r]+bu;
      const float fl = acc[mr][3][r]+bfl, fr = acc[mr][4][r]+bfr2;
      const float cn = sigm(i_)*ftanh(u_) + sigm(fl)*cl + sigm(fr)*cr;
      const float hv = sigm(o_)*ftanh(cn);
      const i64 oidx = (base + s0 + j)*Hd + hcol;
      cbb[oidx] = f2bf(cn);
      hb[oidx]  = f2bf(hv);
      hOut[oidx] = hv;
    }
  }
}

// ---------------------------------------------------------------------------
// Fused small levels d=5..0 v3: one block per tree; kt loop fully unrolled
// with register-double-buffered B (bb[2][2][5]) for ~10 outstanding L2 loads.
// ---------------------------------------------------------------------------
__global__ __launch_bounds__(512)
void tree_fused(const short* __restrict__ WB, const float* __restrict__ b_iou,
                const float* __restrict__ U_f_b, float* __restrict__ hOut,
                const short* __restrict__ hb, const short* __restrict__ cbb,
                float* __restrict__ outRoot){
  __shared__ __align__(16) char BUF[96*1024];
  char* bAh = BUF;
  char* bAc = BUF + 32*1024;
  char* bBh = BUF + 64*1024;
  char* bBc = BUF + 80*1024;
  const int tid = threadIdx.x;
  const int lane = tid & 63, w = tid >> 6;
  const int hhb = w >> 1;
  const int g0 = (w & 1) * 2;
  const int b = blockIdx.x;
  const i64 tb = (i64)b*Tn;

  #pragma unroll
  for (int p=0;p<4;p++){
    int idx = p*512 + tid;
    int row = idx >> 5, ch = idx & 31;
    int off = row*512 + ((ch*16) ^ (((row>>1)&7)<<4));
    *(short8v*)(bAh + off) = *(const short8v*)(hb  + (tb + 63 + row)*Hd + ch*8);
    *(short8v*)(bAc + off) = *(const short8v*)(cbb + (tb + 63 + row)*Hd + ch*8);
  }
  __syncthreads();

  char* inH = bAh; char* inC = bAc; char* outH = bBh; char* outC = bBc;
  const short* bbase = WB + (i64)hhb*163840 + (i64)lane*8;

  for (int d = 5; d >= 0; --d){
    const int M = 1<<d, s0v = M-1;
    const int nmf = (d == 5) ? 2 : 1;
    for (int mf = 0; mf < nmf; ++mf){
      const int j = mf*16 + (lane&15);
      const int qq = lane >> 4;
      float4v acc[2][5];
      #pragma unroll
      for (int c=0;c<2;c++)
        #pragma unroll
        for (int s=0;s<5;s++){ float4v z = {0.f,0.f,0.f,0.f}; acc[c][s] = z; }

      short8v bb[2][2][5];
      #pragma unroll
      for (int c=0;c<2;c++)
        #pragma unroll
        for (int s=0;s<5;s++)
          bb[0][c][s] = *(const short8v*)(bbase + (i64)((g0+c)*5+s)*512);

      #pragma unroll
      for (int kt=0; kt<16; ++kt){
        if (kt+1 < 16){
          const short* bp = bbase + (i64)(kt+1)*10240;
          #pragma unroll
          for (int c=0;c<2;c++)
            #pragma unroll
            for (int s=0;s<5;s++)
              bb[(kt+1)&1][c][s] = *(const short8v*)(bp + (i64)((g0+c)*5+s)*512);
        }
        const int crow = 2*j + (kt>>3);
        const int ccolB = ((kt&7)*32 + qq*8)*2;
        short8v a = *(const short8v*)(inH + crow*512 + (ccolB ^ (((crow>>1)&7)<<4)));
        #pragma unroll
        for (int c=0;c<2;c++)
          #pragma unroll
          for (int s=0;s<5;s++)
            acc[c][s] = __builtin_amdgcn_mfma_f32_16x16x32_bf16(a, bb[kt&1][c][s], acc[c][s], 0, 0, 0);
      }

      #pragma unroll
      for (int c=0;c<2;c++){
        const int hcol = hhb*64 + (g0+c)*16 + (lane&15);
        const float bi = b_iou[hcol], bo = b_iou[256+hcol], bu = b_iou[512+hcol];
        const float bfl = U_f_b[hcol], bfr2 = U_f_b[256+hcol];
        #pragma unroll
        for (int r=0;r<4;r++){
          const int row = mf*16 + qq*4 + r;
          if (row < M){
            const int cxor = (hcol*2) ^ ((row&7)<<4);
            const float cl = bf2f(*(const unsigned short*)(inC + row*1024 + cxor));
            const float cr = bf2f(*(const unsigned short*)(inC + row*1024 + 512 + cxor));
            const float i_ = acc[c][0][r]+bi, o_ = acc[c][1][r]+bo, u_ = acc[c][2][r]+bu;
            const float fl = acc[c][3][r]+bfl, fr = acc[c][4][r]+bfr2;
            const float cn = sigm(i_)*ftanh(u_) + sigm(fl)*cl + sigm(fr)*cr;
            const float hv = sigm(o_)*ftanh(cn);
            const int woff = row*512 + ((hcol*2) ^ (((row>>1)&7)<<4));
            *(short*)(outH + woff) = f2bf(hv);
            *(short*)(outC + woff) = f2bf(cn);
            hOut[(tb + s0v + row)*Hd + hcol] = hv;
            if (d == 0){
              outRoot[b*Hd + hcol] = hv;
              outRoot[Bb*Hd + b*Hd + hcol] = cn;
            }
          }
        }
      }
    }
    __syncthreads();
    char* t;
    t = inH; inH = outH; outH = t;
    t = inC; inC = outC; outC = t;
  }
}

extern "C" void kernel_launch(void* const* d_in, const int* in_sizes, int n_in,
                              void* d_out, int out_size, void* d_ws, size_t ws_size,
                              hipStream_t stream){
  const int*   wordid = (const int*)  d_in[0];
  const float* emb    = (const float*)d_in[6];
  const float* W_iou  = (const float*)d_in[7];
  const float* U_iou  = (const float*)d_in[8];
  const float* b_iou  = (const float*)d_in[9];
  const float* U_f_w  = (const float*)d_in[10];
  const float* U_f_b  = (const float*)d_in[11];

  float* hOut    = (float*)d_out;            // (B,T,H) fp32
  float* outRoot = hOut + NTH;               // root_h then root_c
  short* cbb  = (short*)d_ws;                // c bf16; root rows hold wemb overlay
  short* hb   = cbb + NTH;                   // h bf16; internal rows hold wemb overlay pre-leaf
  short* Wt2I = hb + NTH;                    // 655360 shorts
  short* Wt2L = Wt2I + 655360;               // 196608 shorts

  hipLaunchKernelGGL(prep_kernel, dim3(8608), dim3(256), 0, stream,
                     W_iou, U_iou, U_f_w, Wt2I, Wt2L, wordid, emb, hb, cbb);
  hipLaunchKernelGGL(leaf_gemm, dim3(4096), dim3(512), 0, stream,
                     hb, cbb, Wt2L, b_iou, hOut, hb, cbb);
  for (int d = 9; d >= 6; --d){
    const int s = (1<<d)-1, e = (2<<d)-1;
    hipLaunchKernelGGL(level_gemm, dim3(4<<d), dim3(512), 0, stream,
                       Wt2I, b_iou, U_f_b, hOut, hb, cbb, s, e, d);
  }
  hipLaunchKernelGGL(tree_fused, dim3(64), dim3(512), 0, stream,
                     Wt2I, b_iou, U_f_b, hOut, hb, cbb, outRoot);
}

// Round 23
// 386.453 us; speedup vs baseline: 1.6903x; 1.6903x over previous
//
#include <hip/hip_runtime.h>
#include <math.h>

typedef long long i64;
typedef short short8v __attribute__((ext_vector_type(8)));
typedef float float4v __attribute__((ext_vector_type(4)));

#define Hd 256
#define Bb 64
#define Tn 2047
#define LEAF0 1023
#define NTH 33538048LL   // B*T*H elements

__device__ __forceinline__ float frcp(float x){ return __builtin_amdgcn_rcpf(x); }
__device__ __forceinline__ float sigm(float x){ return frcp(1.0f+__expf(-x)); }
__device__ __forceinline__ float ftanh(float x){ return 1.0f - 2.0f*frcp(__expf(2.0f*x)+1.0f); }
__device__ __forceinline__ float bf2f(unsigned short s){
  union { unsigned u; float f; } v; v.u = ((unsigned)s)<<16; return v.f; }
__device__ __forceinline__ short f2bf(float f){
  union { float f; unsigned u; } v; v.f = f;
  unsigned r = v.u + 0x7FFF + ((v.u>>16)&1);
  return (short)(r>>16); }

#define GL2LDS(gp, lp) __builtin_amdgcn_global_load_lds( \
  (const __attribute__((address_space(1))) void*)(gp), \
  (__attribute__((address_space(3))) void*)(lp), 16, 0, 0)

// ---------------------------------------------------------------------------
// prep (R21 verbatim)
// ---------------------------------------------------------------------------
__global__ __launch_bounds__(256)
void prep_kernel(const float* __restrict__ W_iou, const float* __restrict__ U_iou,
                 const float* __restrict__ U_f_w,
                 short* __restrict__ Wt2I, short* __restrict__ Wt2L,
                 const int* __restrict__ wordid, const float* __restrict__ emb,
                 short* __restrict__ hb, short* __restrict__ cbb){
  if (blockIdx.x < 320){
    int t = blockIdx.x*256 + threadIdx.x;
    int lane = t & 63, rest = t >> 6;
    int nr = rest % 20; int rest2 = rest / 20;
    int kt = rest2 & 15, hhb = rest2 >> 4;
    int g = nr/5, strip = nr - g*5;
    int j = strip*256 + hhb*64 + g*16 + (lane&15);
    int k0 = kt*32 + (lane>>4)*8;
    const float* src = (j < 768) ? (U_iou + (i64)j*512 + k0)
                                 : (U_f_w + (i64)(j-768)*512 + k0);
    short* dst = Wt2I + (i64)t*8;
    #pragma unroll
    for (int e=0;e<8;e++) dst[e] = f2bf(src[e]);
  } else if (blockIdx.x < 416){
    int t2 = (blockIdx.x-320)*256 + threadIdx.x;
    int lane = t2 & 63, rest = t2 >> 6;
    int nr = rest % 12; int rest2 = rest / 12;
    int kt = rest2 & 7, hhb = rest2 >> 3;
    int g = nr/3, strip = nr - g*3;
    int j = strip*256 + hhb*64 + g*16 + (lane&15);
    int k0 = kt*32 + (lane>>4)*8;
    const float* src = W_iou + (i64)j*256 + k0;
    short* dst = Wt2L + (i64)t2*8;
    #pragma unroll
    for (int e=0;e<8;e++) dst[e] = f2bf(src[e]);
  } else {
    int id = (blockIdx.x-416)*256 + threadIdx.x;
    int row = id >> 5, q = id & 31;
    int b = row >> 10, j = row & 1023;
    i64 tb = (i64)b*Tn;
    const int* wid = wordid + (tb + LEAF0 + j)*5;
    float s[8];
    #pragma unroll
    for (int e=0;e<8;e++) s[e] = 0.f;
    #pragma unroll
    for (int l=0;l<5;l++){
      const float* er = emb + (i64)wid[l]*Hd + q*8;
      float4 v0 = *(const float4*)(er);
      float4 v1 = *(const float4*)(er+4);
      s[0]+=v0.x; s[1]+=v0.y; s[2]+=v0.z; s[3]+=v0.w;
      s[4]+=v1.x; s[5]+=v1.y; s[6]+=v1.z; s[7]+=v1.w;
    }
    short o[8];
    #pragma unroll
    for (int e=0;e<8;e++) o[e] = f2bf(s[e]);
    short* dst = (j < 1023) ? (hb + (tb + j)*Hd) : (cbb + tb*Hd);
    *(short8v*)(dst + q*8) = *(short8v*)o;
  }
}

// ---------------------------------------------------------------------------
// Leaf GEMM (R21 verbatim, no c0 read): BK=64, 4 iters, 1 barrier/iter.
// ---------------------------------------------------------------------------
#define LEAF_IT(I, V1, V2)                                                   \
  {                                                                          \
    _Pragma("unroll")                                                        \
    for (int st=0; st<3; ++st)                                               \
      qb[st] = *(const short8v*)(wbB + (i64)((I)*2+1)*12*512 + (i64)st*512); \
    asm volatile("" ::: "memory");                                           \
    if ((I)+2 < 4) GL2LDS(srcA + ((I)+2)*64, &As[(((I)+2)&3)*4096 + w*512]); \
    asm volatile("" ::: "memory");                                           \
    asm volatile("s_waitcnt vmcnt(" #V1 ")" ::: "memory");                   \
    __builtin_amdgcn_s_barrier();                                            \
    asm volatile("" ::: "memory");                                           \
    {                                                                        \
      short8v a0 = *(const short8v*)&As[((I)&3)*4096 + (wm*2+0)*512 + lane*8]; \
      short8v a1 = *(const short8v*)&As[((I)&3)*4096 + (wm*2+1)*512 + lane*8]; \
      _Pragma("unroll")                                                      \
      for (int st=0; st<3; ++st){                                            \
        acc[0][st] = __builtin_amdgcn_mfma_f32_16x16x32_bf16(a0, pb[st], acc[0][st], 0,0,0); \
        acc[1][st] = __builtin_amdgcn_mfma_f32_16x16x32_bf16(a1, pb[st], acc[1][st], 0,0,0); \
      }                                                                      \
    }                                                                        \
    asm volatile("" ::: "memory");                                           \
    if ((I)+1 < 4){                                                          \
      _Pragma("unroll")                                                      \
      for (int st=0; st<3; ++st)                                             \
        pb[st] = *(const short8v*)(wbB + (i64)((I)+1)*2*12*512 + (i64)st*512); \
    }                                                                        \
    asm volatile("" ::: "memory");                                           \
    asm volatile("s_waitcnt vmcnt(" #V2 ")" ::: "memory");                   \
    {                                                                        \
      short8v a0 = *(const short8v*)&As[((I)&3)*4096 + 2048 + (wm*2+0)*512 + lane*8]; \
      short8v a1 = *(const short8v*)&As[((I)&3)*4096 + 2048 + (wm*2+1)*512 + lane*8]; \
      _Pragma("unroll")                                                      \
      for (int st=0; st<3; ++st){                                            \
        acc[0][st] = __builtin_amdgcn_mfma_f32_16x16x32_bf16(a0, qb[st], acc[0][st], 0,0,0); \
        acc[1][st] = __builtin_amdgcn_mfma_f32_16x16x32_bf16(a1, qb[st], acc[1][st], 0,0,0); \
      }                                                                      \
    }                                                                        \
    asm volatile("s_waitcnt lgkmcnt(0)" ::: "memory");                       \
  }

__global__ __launch_bounds__(512, 4)
void leaf_gemm(const short* __restrict__ hb, const short* __restrict__ cbb,
               const short* __restrict__ WB,
               const float* __restrict__ b_iou,
               float* __restrict__ hOut, short* __restrict__ hbOut,
               short* __restrict__ cbbOut){
  __shared__ __align__(16) short As[4*4096];   // 32 KB ring-4
  const int tid = threadIdx.x;
  const int lane = tid & 63, w = tid >> 6;
  const int wm = w >> 2, wg = w & 3;           // output role
  const int bid = blockIdx.x;
  const int hhb = bid & 3;
  const int m0 = (bid >> 2) * 64;

  const short* srcA;                            // staging role: rg=w&3, sub=w>>2
  {
    const int r = m0 + (w&3)*16 + (lane&15);
    const int bA = r >> 10, jA = r & 1023;
    srcA = ((jA < 1023) ? (hb + ((i64)bA*Tn + jA)*Hd) : (cbb + (i64)bA*Tn*Hd))
           + (w>>2)*32 + (lane>>4)*8;
  }
  const short* wbB = WB + (i64)hhb*96*512 + (i64)(wg*3)*512 + lane*8;

  float4v acc[2][3];
  #pragma unroll
  for (int mr=0;mr<2;mr++)
    #pragma unroll
    for (int st=0;st<3;st++){ float4v z = {0.f,0.f,0.f,0.f}; acc[mr][st] = z; }

  short8v pb[3], qb[3];
  #pragma unroll
  for (int st=0; st<3; ++st) pb[st] = *(const short8v*)(wbB + (i64)st*512);
  asm volatile("" ::: "memory");
  GL2LDS(srcA,      &As[0*4096 + w*512]);
  GL2LDS(srcA + 64, &As[1*4096 + w*512]);
  asm volatile("" ::: "memory");

  LEAF_IT(0,5,4)  LEAF_IT(1,4,4)  LEAF_IT(2,3,3)  LEAF_IT(3,3,0)

  const int hcol = hhb*64 + wg*16 + (lane&15);
  const float bi = b_iou[hcol], bo = b_iou[256+hcol], bu = b_iou[512+hcol];
  #pragma unroll
  for (int mr=0;mr<2;mr++){
    const int mgb = m0 + wm*32 + mr*16 + ((lane>>4)<<2);
    #pragma unroll
    for (int r=0;r<4;r++){
      const int m = mgb + r;
      const int b = m >> 10, j = m & 1023;
      const i64 n = (i64)b*Tn + LEAF0 + j;
      const float i_ = acc[mr][0][r] + bi;
      const float o_ = acc[mr][1][r] + bo;
      const float u_ = acc[mr][2][r] + bu;
      const float cn = sigm(i_)*ftanh(u_);            // c0 == 0 for this problem
      const float hv = sigm(o_)*ftanh(cn);
      cbbOut[n*Hd + hcol] = f2bf(cn);
      hbOut[n*Hd + hcol]  = f2bf(hv);
      hOut[n*Hd + hcol] = hv;
    }
  }
}

// ---------------------------------------------------------------------------
// Internal level d=9..5 (R21 verbatim body): BK=64, 8 iters, 1 barrier/iter.
// ---------------------------------------------------------------------------
#define LVL_IT(I, V1, V2)                                                    \
  {                                                                          \
    _Pragma("unroll")                                                        \
    for (int st=0; st<5; ++st)                                               \
      qb[st] = *(const short8v*)(wbB + (i64)((I)*2+1)*20*512 + (i64)st*512); \
    asm volatile("" ::: "memory");                                           \
    if ((I)+2 < 8) GL2LDS(srcA + ((I)+2)*64, &As[(((I)+2)&3)*4096 + w*512]); \
    asm volatile("" ::: "memory");                                           \
    asm volatile("s_waitcnt vmcnt(" #V1 ")" ::: "memory");                   \
    __builtin_amdgcn_s_barrier();                                            \
    asm volatile("" ::: "memory");                                           \
    {                                                                        \
      short8v a0 = *(const short8v*)&As[((I)&3)*4096 + (wm*2+0)*512 + lane*8]; \
      short8v a1 = *(const short8v*)&As[((I)&3)*4096 + (wm*2+1)*512 + lane*8]; \
      _Pragma("unroll")                                                      \
      for (int st=0; st<5; ++st){                                            \
        acc[0][st] = __builtin_amdgcn_mfma_f32_16x16x32_bf16(a0, pb[st], acc[0][st], 0,0,0); \
        acc[1][st] = __builtin_amdgcn_mfma_f32_16x16x32_bf16(a1, pb[st], acc[1][st], 0,0,0); \
      }                                                                      \
    }                                                                        \
    asm volatile("" ::: "memory");                                           \
    if ((I)+1 < 8){                                                          \
      _Pragma("unroll")                                                      \
      for (int st=0; st<5; ++st)                                             \
        pb[st] = *(const short8v*)(wbB + (i64)((I)+1)*2*20*512 + (i64)st*512); \
    }                                                                        \
    asm volatile("" ::: "memory");                                           \
    asm volatile("s_waitcnt vmcnt(" #V2 ")" ::: "memory");                   \
    {                                                                        \
      short8v a0 = *(const short8v*)&As[((I)&3)*4096 + 2048 + (wm*2+0)*512 + lane*8]; \
      short8v a1 = *(const short8v*)&As[((I)&3)*4096 + 2048 + (wm*2+1)*512 + lane*8]; \
      _Pragma("unroll")                                                      \
      for (int st=0; st<5; ++st){                                            \
        acc[0][st] = __builtin_amdgcn_mfma_f32_16x16x32_bf16(a0, qb[st], acc[0][st], 0,0,0); \
        acc[1][st] = __builtin_amdgcn_mfma_f32_16x16x32_bf16(a1, qb[st], acc[1][st], 0,0,0); \
      }                                                                      \
    }                                                                        \
    asm volatile("s_waitcnt lgkmcnt(0)" ::: "memory");                       \
  }

__global__ __launch_bounds__(512, 4)
void level_gemm(const short* __restrict__ WB,
                const float* __restrict__ b_iou, const float* __restrict__ U_f_b,
                float* __restrict__ hOut, short* __restrict__ hb, short* __restrict__ cbb,
                int s0, int e0, int logn){
  __shared__ __align__(16) short As[4*4096];   // 32 KB ring-4
  const int tid = threadIdx.x;
  const int lane = tid & 63, w = tid >> 6;
  const int wm = w >> 2, wg = w & 3;
  const int bid = blockIdx.x;
  const int hhb = bid & 3;
  const int m0 = (bid >> 2) * 64;
  const int nm1 = (1<<logn)-1;

  const short* srcA;
  {
    const int r = m0 + (w&3)*16 + (lane&15);
    const int bA = r >> logn, jA = r & nm1;
    srcA = hb + ((i64)bA*Tn + e0)*Hd + (i64)jA*512 + (w>>2)*32 + (lane>>4)*8;
  }
  const short* wbB = WB + (i64)hhb*320*512 + (i64)(wg*5)*512 + lane*8;

  float4v acc[2][5];
  #pragma unroll
  for (int mr=0;mr<2;mr++)
    #pragma unroll
    for (int st=0;st<5;st++){ float4v z = {0.f,0.f,0.f,0.f}; acc[mr][st] = z; }

  short8v pb[5], qb[5];
  #pragma unroll
  for (int st=0; st<5; ++st) pb[st] = *(const short8v*)(wbB + (i64)st*512);
  asm volatile("" ::: "memory");
  GL2LDS(srcA,      &As[0*4096 + w*512]);
  GL2LDS(srcA + 64, &As[1*4096 + w*512]);
  asm volatile("" ::: "memory");

  LVL_IT(0,7,6)  LVL_IT(1,6,6)  LVL_IT(2,6,6)  LVL_IT(3,6,6)
  LVL_IT(4,6,6)  LVL_IT(5,6,6)  LVL_IT(6,5,5)  LVL_IT(7,5,0)

  const int hcol = hhb*64 + wg*16 + (lane&15);
  const float bi = b_iou[hcol], bo = b_iou[256+hcol], bu = b_iou[512+hcol];
  const float bfl = U_f_b[hcol], bfr2 = U_f_b[256+hcol];
  #pragma unroll
  for (int mr=0;mr<2;mr++){
    const int mgb = m0 + wm*32 + mr*16 + ((lane>>4)<<2);
    #pragma unroll
    for (int r=0;r<4;r++){
      const int m = mgb + r;
      const int b = m >> logn, j = m & nm1;
      const i64 base = (i64)b*Tn;
      const i64 cidx = (base + e0 + 2*j)*Hd + hcol;
      const float cl = bf2f((unsigned short)cbb[cidx]);
      const float cr = bf2f((unsigned short)cbb[cidx + Hd]);
      const float i_ = acc[mr][0][r]+bi, o_ = acc[mr][1][r]+bo, u_ = acc[mr][2][r]+bu;
      const float fl = acc[mr][3][r]+bfl, fr = acc[mr][4][r]+bfr2;
      const float cn = sigm(i_)*ftanh(u_) + sigm(fl)*cl + sigm(fr)*cr;
      const float hv = sigm(o_)*ftanh(cn);
      const i64 oidx = (base + s0 + j)*Hd + hcol;
      cbb[oidx] = f2bf(cn);
      hb[oidx]  = f2bf(hv);
      hOut[oidx] = hv;
    }
  }
}

// ---------------------------------------------------------------------------
// Fused small levels d=4..0 (R21 v2 body, staging shifted to rows 31..62):
// one block per tree, 8 waves; wave = 2 colgroups x 5 strips; children h/c
// ping-pong in XOR-swizzled LDS; B from L2; 1 barrier/level.
// ---------------------------------------------------------------------------
__global__ __launch_bounds__(512)
void tree_fused(const short* __restrict__ WB, const float* __restrict__ b_iou,
                const float* __restrict__ U_f_b, float* __restrict__ hOut,
                const short* __restrict__ hb, const short* __restrict__ cbb,
                float* __restrict__ outRoot){
  __shared__ __align__(16) char BUF[48*1024];
  char* bAh = BUF;             // 32 rows x 512B
  char* bAc = BUF + 16*1024;   // 32 rows
  char* bBh = BUF + 32*1024;   // 16 rows
  char* bBc = BUF + 40*1024;   // 16 rows
  const int tid = threadIdx.x;
  const int lane = tid & 63, w = tid >> 6;
  const int hhb = w >> 1;
  const int g0 = (w & 1) * 2;
  const int b = blockIdx.x;
  const i64 tb = (i64)b*Tn;

  // stage level-4 children: tree rows 31..62 (32 rows) of h and c
  #pragma unroll
  for (int p=0;p<2;p++){
    int idx = p*512 + tid;
    int row = idx >> 5, ch = idx & 31;
    int off = row*512 + ((ch*16) ^ (((row>>1)&7)<<4));
    *(short8v*)(bAh + off) = *(const short8v*)(hb  + (tb + 31 + row)*Hd + ch*8);
    *(short8v*)(bAc + off) = *(const short8v*)(cbb + (tb + 31 + row)*Hd + ch*8);
  }
  __syncthreads();

  char* inH = bAh; char* inC = bAc; char* outH = bBh; char* outC = bBc;

  for (int d = 4; d >= 0; --d){
    const int M = 1<<d, s0v = M-1;
    {
      const int j = lane & 15;
      const int qq = lane >> 4;
      float4v acc[2][5];
      #pragma unroll
      for (int c=0;c<2;c++)
        #pragma unroll
        for (int s=0;s<5;s++){ float4v z = {0.f,0.f,0.f,0.f}; acc[c][s] = z; }
      #pragma unroll 2
      for (int kt=0; kt<16; ++kt){
        const int crow = 2*j + (kt>>3);
        const int ccolB = ((kt&7)*32 + qq*8)*2;
        short8v a = *(const short8v*)(inH + crow*512 + (ccolB ^ (((crow>>1)&7)<<4)));
        const short* bp = WB + (i64)hhb*163840 + (i64)kt*10240 + (i64)lane*8;
        #pragma unroll
        for (int c=0;c<2;c++)
          #pragma unroll
          for (int s=0;s<5;s++){
            short8v bb = *(const short8v*)(bp + (i64)((g0+c)*5+s)*512);
            acc[c][s] = __builtin_amdgcn_mfma_f32_16x16x32_bf16(a, bb, acc[c][s], 0, 0, 0);
          }
      }
      #pragma unroll
      for (int c=0;c<2;c++){
        const int hcol = hhb*64 + (g0+c)*16 + (lane&15);
        const float bi = b_iou[hcol], bo = b_iou[256+hcol], bu = b_iou[512+hcol];
        const float bfl = U_f_b[hcol], bfr2 = U_f_b[256+hcol];
        #pragma unroll
        for (int r=0;r<4;r++){
          const int row = qq*4 + r;
          if (row < M){
            const int cxor = (hcol*2) ^ ((row&7)<<4);
            const float cl = bf2f(*(const unsigned short*)(inC + row*1024 + cxor));
            const float cr = bf2f(*(const unsigned short*)(inC + row*1024 + 512 + cxor));
            const float i_ = acc[c][0][r]+bi, o_ = acc[c][1][r]+bo, u_ = acc[c][2][r]+bu;
            const float fl = acc[c][3][r]+bfl, fr = acc[c][4][r]+bfr2;
            const float cn = sigm(i_)*ftanh(u_) + sigm(fl)*cl + sigm(fr)*cr;
            const float hv = sigm(o_)*ftanh(cn);
            const int woff = row*512 + ((hcol*2) ^ (((row>>1)&7)<<4));
            *(short*)(outH + woff) = f2bf(hv);
            *(short*)(outC + woff) = f2bf(cn);
            hOut[(tb + s0v + row)*Hd + hcol] = hv;
            if (d == 0){
              outRoot[b*Hd + hcol] = hv;
              outRoot[Bb*Hd + b*Hd + hcol] = cn;
            }
          }
        }
      }
    }
    __syncthreads();
    char* t;
    t = inH; inH = outH; outH = t;
    t = inC; inC = outC; outC = t;
  }
}

extern "C" void kernel_launch(void* const* d_in, const int* in_sizes, int n_in,
                              void* d_out, int out_size, void* d_ws, size_t ws_size,
                              hipStream_t stream){
  const int*   wordid = (const int*)  d_in[0];
  const float* emb    = (const float*)d_in[6];
  const float* W_iou  = (const float*)d_in[7];
  const float* U_iou  = (const float*)d_in[8];
  const float* b_iou  = (const float*)d_in[9];
  const float* U_f_w  = (const float*)d_in[10];
  const float* U_f_b  = (const float*)d_in[11];

  float* hOut    = (float*)d_out;            // (B,T,H) fp32
  float* outRoot = hOut + NTH;               // root_h then root_c
  short* cbb  = (short*)d_ws;                // c bf16; root rows hold wemb overlay
  short* hb   = cbb + NTH;                   // h bf16; internal rows hold wemb overlay pre-leaf
  short* Wt2I = hb + NTH;                    // 655360 shorts
  short* Wt2L = Wt2I + 655360;               // 196608 shorts

  hipLaunchKernelGGL(prep_kernel, dim3(8608), dim3(256), 0, stream,
                     W_iou, U_iou, U_f_w, Wt2I, Wt2L, wordid, emb, hb, cbb);
  hipLaunchKernelGGL(leaf_gemm, dim3(4096), dim3(512), 0, stream,
                     hb, cbb, Wt2L, b_iou, hOut, hb, cbb);
  for (int d = 9; d >= 5; --d){
    const int s = (1<<d)-1, e = (2<<d)-1;
    hipLaunchKernelGGL(level_gemm, dim3(4<<d), dim3(512), 0, stream,
                       Wt2I, b_iou, U_f_b, hOut, hb, cbb, s, e, d);
  }
  hipLaunchKernelGGL(tree_fused, dim3(64), dim3(512), 0, stream,
                     Wt2I, b_iou, U_f_b, hOut, hb, cbb, outRoot);
}

// Round 24
// 349.827 us; speedup vs baseline: 1.8673x; 1.1047x over previous
//
#include <hip/hip_runtime.h>
#include <math.h>

typedef long long i64;
typedef short short8v __attribute__((ext_vector_type(8)));
typedef float float4v __attribute__((ext_vector_type(4)));

#define Hd 256
#define Bb 64
#define Tn 2047
#define LEAF0 1023
#define NTH 33538048LL   // B*T*H elements

__device__ __forceinline__ float frcp(float x){ return __builtin_amdgcn_rcpf(x); }
__device__ __forceinline__ float sigm(float x){ return frcp(1.0f+__expf(-x)); }
__device__ __forceinline__ float ftanh(float x){ return 1.0f - 2.0f*frcp(__expf(2.0f*x)+1.0f); }
__device__ __forceinline__ float bf2f(unsigned short s){
  union { unsigned u; float f; } v; v.u = ((unsigned)s)<<16; return v.f; }
__device__ __forceinline__ short f2bf(float f){
  union { float f; unsigned u; } v; v.f = f;
  unsigned r = v.u + 0x7FFF + ((v.u>>16)&1);
  return (short)(r>>16); }

#define GL2LDS(gp, lp) __builtin_amdgcn_global_load_lds( \
  (const __attribute__((address_space(1))) void*)(gp), \
  (__attribute__((address_space(3))) void*)(lp), 16, 0, 0)

// ---------------------------------------------------------------------------
// prep: [0,320) Wt2I pack; [320,416) Wt2L pack; rest wemb overlay
// (leaf j<1023 -> hb internal row b*Tn+j; j==1023 -> cbb root row).
// ---------------------------------------------------------------------------
__global__ __launch_bounds__(256)
void prep_kernel(const float* __restrict__ W_iou, const float* __restrict__ U_iou,
                 const float* __restrict__ U_f_w,
                 short* __restrict__ Wt2I, short* __restrict__ Wt2L,
                 const int* __restrict__ wordid, const float* __restrict__ emb,
                 short* __restrict__ hb, short* __restrict__ cbb){
  if (blockIdx.x < 320){
    int t = blockIdx.x*256 + threadIdx.x;
    int lane = t & 63, rest = t >> 6;
    int nr = rest % 20; int rest2 = rest / 20;
    int kt = rest2 & 15, hhb = rest2 >> 4;
    int g = nr/5, strip = nr - g*5;
    int j = strip*256 + hhb*64 + g*16 + (lane&15);
    int k0 = kt*32 + (lane>>4)*8;
    const float* src = (j < 768) ? (U_iou + (i64)j*512 + k0)
                                 : (U_f_w + (i64)(j-768)*512 + k0);
    short* dst = Wt2I + (i64)t*8;
    #pragma unroll
    for (int e=0;e<8;e++) dst[e] = f2bf(src[e]);
  } else if (blockIdx.x < 416){
    int t2 = (blockIdx.x-320)*256 + threadIdx.x;
    int lane = t2 & 63, rest = t2 >> 6;
    int nr = rest % 12; int rest2 = rest / 12;
    int kt = rest2 & 7, hhb = rest2 >> 3;
    int g = nr/3, strip = nr - g*3;
    int j = strip*256 + hhb*64 + g*16 + (lane&15);
    int k0 = kt*32 + (lane>>4)*8;
    const float* src = W_iou + (i64)j*256 + k0;
    short* dst = Wt2L + (i64)t2*8;
    #pragma unroll
    for (int e=0;e<8;e++) dst[e] = f2bf(src[e]);
  } else {
    int id = (blockIdx.x-416)*256 + threadIdx.x;
    int row = id >> 5, q = id & 31;
    int b = row >> 10, j = row & 1023;
    i64 tb = (i64)b*Tn;
    const int* wid = wordid + (tb + LEAF0 + j)*5;
    float s[8];
    #pragma unroll
    for (int e=0;e<8;e++) s[e] = 0.f;
    #pragma unroll
    for (int l=0;l<5;l++){
      const float* er = emb + (i64)wid[l]*Hd + q*8;
      float4 v0 = *(const float4*)(er);
      float4 v1 = *(const float4*)(er+4);
      s[0]+=v0.x; s[1]+=v0.y; s[2]+=v0.z; s[3]+=v0.w;
      s[4]+=v1.x; s[5]+=v1.y; s[6]+=v1.z; s[7]+=v1.w;
    }
    short o[8];
    #pragma unroll
    for (int e=0;e<8;e++) o[e] = f2bf(s[e]);
    short* dst = (j < 1023) ? (hb + (tb + j)*Hd) : (cbb + tb*Hd);
    *(short8v*)(dst + q*8) = *(short8v*)o;
  }
}

// ---------------------------------------------------------------------------
// Leaf GEMM (no c0 read — c0 is identically zero in this problem):
// BK=64, 4 iters, 1 barrier/iter. Block 64 rows x 64 hcols, 8 waves; wave
// output = 32 rows (acc[2][3]) x 16 hcols x {i,o,u}. A: ring-4 LDS (32 KB),
// staged 2 ahead; B regs pb/qb; counted vmcnt.
// ---------------------------------------------------------------------------
#define LEAF_IT(I, V1, V2)                                                   \
  {                                                                          \
    _Pragma("unroll")                                                        \
    for (int st=0; st<3; ++st)                                               \
      qb[st] = *(const short8v*)(wbB + (i64)((I)*2+1)*12*512 + (i64)st*512); \
    asm volatile("" ::: "memory");                                           \
    if ((I)+2 < 4) GL2LDS(srcA + ((I)+2)*64, &As[(((I)+2)&3)*4096 + w*512]); \
    asm volatile("" ::: "memory");                                           \
    asm volatile("s_waitcnt vmcnt(" #V1 ")" ::: "memory");                   \
    __builtin_amdgcn_s_barrier();                                            \
    asm volatile("" ::: "memory");                                           \
    {                                                                        \
      short8v a0 = *(const short8v*)&As[((I)&3)*4096 + (wm*2+0)*512 + lane*8]; \
      short8v a1 = *(const short8v*)&As[((I)&3)*4096 + (wm*2+1)*512 + lane*8]; \
      _Pragma("unroll")                                                      \
      for (int st=0; st<3; ++st){                                            \
        acc[0][st] = __builtin_amdgcn_mfma_f32_16x16x32_bf16(a0, pb[st], acc[0][st], 0,0,0); \
        acc[1][st] = __builtin_amdgcn_mfma_f32_16x16x32_bf16(a1, pb[st], acc[1][st], 0,0,0); \
      }                                                                      \
    }                                                                        \
    asm volatile("" ::: "memory");                                           \
    if ((I)+1 < 4){                                                          \
      _Pragma("unroll")                                                      \
      for (int st=0; st<3; ++st)                                             \
        pb[st] = *(const short8v*)(wbB + (i64)((I)+1)*2*12*512 + (i64)st*512); \
    }                                                                        \
    asm volatile("" ::: "memory");                                           \
    asm volatile("s_waitcnt vmcnt(" #V2 ")" ::: "memory");                   \
    {                                                                        \
      short8v a0 = *(const short8v*)&As[((I)&3)*4096 + 2048 + (wm*2+0)*512 + lane*8]; \
      short8v a1 = *(const short8v*)&As[((I)&3)*4096 + 2048 + (wm*2+1)*512 + lane*8]; \
      _Pragma("unroll")                                                      \
      for (int st=0; st<3; ++st){                                            \
        acc[0][st] = __builtin_amdgcn_mfma_f32_16x16x32_bf16(a0, qb[st], acc[0][st], 0,0,0); \
        acc[1][st] = __builtin_amdgcn_mfma_f32_16x16x32_bf16(a1, qb[st], acc[1][st], 0,0,0); \
      }                                                                      \
    }                                                                        \
    asm volatile("s_waitcnt lgkmcnt(0)" ::: "memory");                       \
  }

__global__ __launch_bounds__(512, 4)
void leaf_gemm(const short* __restrict__ hb, const short* __restrict__ cbb,
               const short* __restrict__ WB,
               const float* __restrict__ b_iou,
               float* __restrict__ hOut, short* __restrict__ hbOut,
               short* __restrict__ cbbOut){
  __shared__ __align__(16) short As[4*4096];   // 32 KB ring-4
  const int tid = threadIdx.x;
  const int lane = tid & 63, w = tid >> 6;
  const int wm = w >> 2, wg = w & 3;           // output role
  const int bid = blockIdx.x;
  const int hhb = bid & 3;
  const int m0 = (bid >> 2) * 64;

  const short* srcA;                            // staging role: rg=w&3, sub=w>>2
  {
    const int r = m0 + (w&3)*16 + (lane&15);
    const int bA = r >> 10, jA = r & 1023;
    srcA = ((jA < 1023) ? (hb + ((i64)bA*Tn + jA)*Hd) : (cbb + (i64)bA*Tn*Hd))
           + (w>>2)*32 + (lane>>4)*8;
  }
  const short* wbB = WB + (i64)hhb*96*512 + (i64)(wg*3)*512 + lane*8;

  float4v acc[2][3];
  #pragma unroll
  for (int mr=0;mr<2;mr++)
    #pragma unroll
    for (int st=0;st<3;st++){ float4v z = {0.f,0.f,0.f,0.f}; acc[mr][st] = z; }

  short8v pb[3], qb[3];
  #pragma unroll
  for (int st=0; st<3; ++st) pb[st] = *(const short8v*)(wbB + (i64)st*512);
  asm volatile("" ::: "memory");
  GL2LDS(srcA,      &As[0*4096 + w*512]);
  GL2LDS(srcA + 64, &As[1*4096 + w*512]);
  asm volatile("" ::: "memory");

  LEAF_IT(0,5,4)  LEAF_IT(1,4,4)  LEAF_IT(2,3,3)  LEAF_IT(3,3,0)

  const int hcol = hhb*64 + wg*16 + (lane&15);
  const float bi = b_iou[hcol], bo = b_iou[256+hcol], bu = b_iou[512+hcol];
  #pragma unroll
  for (int mr=0;mr<2;mr++){
    const int mgb = m0 + wm*32 + mr*16 + ((lane>>4)<<2);
    #pragma unroll
    for (int r=0;r<4;r++){
      const int m = mgb + r;
      const int b = m >> 10, j = m & 1023;
      const i64 n = (i64)b*Tn + LEAF0 + j;
      const float i_ = acc[mr][0][r] + bi;
      const float o_ = acc[mr][1][r] + bo;
      const float u_ = acc[mr][2][r] + bu;
      const float cn = sigm(i_)*ftanh(u_);            // c0 == 0 for this problem
      const float hv = sigm(o_)*ftanh(cn);
      cbbOut[n*Hd + hcol] = f2bf(cn);
      hbOut[n*Hd + hcol]  = f2bf(hv);
      hOut[n*Hd + hcol] = hv;
    }
  }
}

// ---------------------------------------------------------------------------
// Internal level d=9..6: BK=64, 8 iters, 1 barrier/iter. Block 64 rows x
// 64 hcols, 8 waves; wave = 32 rows (acc[2][5]) x 16 hcols. A ring-4 (32 KB)
// staged 2 ahead; B regs pb/qb. vmcnt: V1=[7,6,...,5,5] V2=[6,...,5,0].
// ---------------------------------------------------------------------------
#define LVL_IT(I, V1, V2)                                                    \
  {                                                                          \
    _Pragma("unroll")                                                        \
    for (int st=0; st<5; ++st)                                               \
      qb[st] = *(const short8v*)(wbB + (i64)((I)*2+1)*20*512 + (i64)st*512); \
    asm volatile("" ::: "memory");                                           \
    if ((I)+2 < 8) GL2LDS(srcA + ((I)+2)*64, &As[(((I)+2)&3)*4096 + w*512]); \
    asm volatile("" ::: "memory");                                           \
    asm volatile("s_waitcnt vmcnt(" #V1 ")" ::: "memory");                   \
    __builtin_amdgcn_s_barrier();                                            \
    asm volatile("" ::: "memory");                                           \
    {                                                                        \
      short8v a0 = *(const short8v*)&As[((I)&3)*4096 + (wm*2+0)*512 + lane*8]; \
      short8v a1 = *(const short8v*)&As[((I)&3)*4096 + (wm*2+1)*512 + lane*8]; \
      _Pragma("unroll")                                                      \
      for (int st=0; st<5; ++st){                                            \
        acc[0][st] = __builtin_amdgcn_mfma_f32_16x16x32_bf16(a0, pb[st], acc[0][st], 0,0,0); \
        acc[1][st] = __builtin_amdgcn_mfma_f32_16x16x32_bf16(a1, pb[st], acc[1][st], 0,0,0); \
      }                                                                      \
    }                                                                        \
    asm volatile("" ::: "memory");                                           \
    if ((I)+1 < 8){                                                          \
      _Pragma("unroll")                                                      \
      for (int st=0; st<5; ++st)                                             \
        pb[st] = *(const short8v*)(wbB + (i64)((I)+1)*2*20*512 + (i64)st*512); \
    }                                                                        \
    asm volatile("" ::: "memory");                                           \
    asm volatile("s_waitcnt vmcnt(" #V2 ")" ::: "memory");                   \
    {                                                                        \
      short8v a0 = *(const short8v*)&As[((I)&3)*4096 + 2048 + (wm*2+0)*512 + lane*8]; \
      short8v a1 = *(const short8v*)&As[((I)&3)*4096 + 2048 + (wm*2+1)*512 + lane*8]; \
      _Pragma("unroll")                                                      \
      for (int st=0; st<5; ++st){                                            \
        acc[0][st] = __builtin_amdgcn_mfma_f32_16x16x32_bf16(a0, qb[st], acc[0][st], 0,0,0); \
        acc[1][st] = __builtin_amdgcn_mfma_f32_16x16x32_bf16(a1, qb[st], acc[1][st], 0,0,0); \
      }                                                                      \
    }                                                                        \
    asm volatile("s_waitcnt lgkmcnt(0)" ::: "memory");                       \
  }

__global__ __launch_bounds__(512, 4)
void level_gemm(const short* __restrict__ WB,
                const float* __restrict__ b_iou, const float* __restrict__ U_f_b,
                float* __restrict__ hOut, short* __restrict__ hb, short* __restrict__ cbb,
                int s0, int e0, int logn){
  __shared__ __align__(16) short As[4*4096];   // 32 KB ring-4
  const int tid = threadIdx.x;
  const int lane = tid & 63, w = tid >> 6;
  const int wm = w >> 2, wg = w & 3;
  const int bid = blockIdx.x;
  const int hhb = bid & 3;
  const int m0 = (bid >> 2) * 64;
  const int nm1 = (1<<logn)-1;

  const short* srcA;
  {
    const int r = m0 + (w&3)*16 + (lane&15);
    const int bA = r >> logn, jA = r & nm1;
    srcA = hb + ((i64)bA*Tn + e0)*Hd + (i64)jA*512 + (w>>2)*32 + (lane>>4)*8;
  }
  const short* wbB = WB + (i64)hhb*320*512 + (i64)(wg*5)*512 + lane*8;

  float4v acc[2][5];
  #pragma unroll
  for (int mr=0;mr<2;mr++)
    #pragma unroll
    for (int st=0;st<5;st++){ float4v z = {0.f,0.f,0.f,0.f}; acc[mr][st] = z; }

  short8v pb[5], qb[5];
  #pragma unroll
  for (int st=0; st<5; ++st) pb[st] = *(const short8v*)(wbB + (i64)st*512);
  asm volatile("" ::: "memory");
  GL2LDS(srcA,      &As[0*4096 + w*512]);
  GL2LDS(srcA + 64, &As[1*4096 + w*512]);
  asm volatile("" ::: "memory");

  LVL_IT(0,7,6)  LVL_IT(1,6,6)  LVL_IT(2,6,6)  LVL_IT(3,6,6)
  LVL_IT(4,6,6)  LVL_IT(5,6,6)  LVL_IT(6,5,5)  LVL_IT(7,5,0)

  const int hcol = hhb*64 + wg*16 + (lane&15);
  const float bi = b_iou[hcol], bo = b_iou[256+hcol], bu = b_iou[512+hcol];
  const float bfl = U_f_b[hcol], bfr2 = U_f_b[256+hcol];
  #pragma unroll
  for (int mr=0;mr<2;mr++){
    const int mgb = m0 + wm*32 + mr*16 + ((lane>>4)<<2);
    #pragma unroll
    for (int r=0;r<4;r++){
      const int m = mgb + r;
      const int b = m >> logn, j = m & nm1;
      const i64 base = (i64)b*Tn;
      const i64 cidx = (base + e0 + 2*j)*Hd + hcol;
      const float cl = bf2f((unsigned short)cbb[cidx]);
      const float cr = bf2f((unsigned short)cbb[cidx + Hd]);
      const float i_ = acc[mr][0][r]+bi, o_ = acc[mr][1][r]+bo, u_ = acc[mr][2][r]+bu;
      const float fl = acc[mr][3][r]+bfl, fr = acc[mr][4][r]+bfr2;
      const float cn = sigm(i_)*ftanh(u_) + sigm(fl)*cl + sigm(fr)*cr;
      const float hv = sigm(o_)*ftanh(cn);
      const i64 oidx = (base + s0 + j)*Hd + hcol;
      cbb[oidx] = f2bf(cn);
      hb[oidx]  = f2bf(hv);
      hOut[oidx] = hv;
    }
  }
}

// ---------------------------------------------------------------------------
// Fused small levels d=5..0 (v2): one block per tree, 8 waves all busy.
// Wave = 2 colgroups x 5 strips; children h/c ping-pong in XOR-swizzled LDS;
// B from L2; 1 barrier/level.
// ---------------------------------------------------------------------------
__global__ __launch_bounds__(512)
void tree_fused(const short* __restrict__ WB, const float* __restrict__ b_iou,
                const float* __restrict__ U_f_b, float* __restrict__ hOut,
                const short* __restrict__ hb, const short* __restrict__ cbb,
                float* __restrict__ outRoot){
  __shared__ __align__(16) char BUF[96*1024];
  char* bAh = BUF;
  char* bAc = BUF + 32*1024;
  char* bBh = BUF + 64*1024;
  char* bBc = BUF + 80*1024;
  const int tid = threadIdx.x;
  const int lane = tid & 63, w = tid >> 6;
  const int hhb = w >> 1;
  const int g0 = (w & 1) * 2;
  const int b = blockIdx.x;
  const i64 tb = (i64)b*Tn;

  #pragma unroll
  for (int p=0;p<4;p++){
    int idx = p*512 + tid;
    int row = idx >> 5, ch = idx & 31;
    int off = row*512 + ((ch*16) ^ (((row>>1)&7)<<4));
    *(short8v*)(bAh + off) = *(const short8v*)(hb  + (tb + 63 + row)*Hd + ch*8);
    *(short8v*)(bAc + off) = *(const short8v*)(cbb + (tb + 63 + row)*Hd + ch*8);
  }
  __syncthreads();

  char* inH = bAh; char* inC = bAc; char* outH = bBh; char* outC = bBc;

  for (int d = 5; d >= 0; --d){
    const int M = 1<<d, s0v = M-1;
    const int nmf = (d == 5) ? 2 : 1;
    for (int mf = 0; mf < nmf; ++mf){
      const int j = mf*16 + (lane&15);
      const int qq = lane >> 4;
      float4v acc[2][5];
      #pragma unroll
      for (int c=0;c<2;c++)
        #pragma unroll
        for (int s=0;s<5;s++){ float4v z = {0.f,0.f,0.f,0.f}; acc[c][s] = z; }
      #pragma unroll 2
      for (int kt=0; kt<16; ++kt){
        const int crow = 2*j + (kt>>3);
        const int ccolB = ((kt&7)*32 + qq*8)*2;
        short8v a = *(const short8v*)(inH + crow*512 + (ccolB ^ (((crow>>1)&7)<<4)));
        const short* bp = WB + (i64)hhb*163840 + (i64)kt*10240 + (i64)lane*8;
        #pragma unroll
        for (int c=0;c<2;c++)
          #pragma unroll
          for (int s=0;s<5;s++){
            short8v bb = *(const short8v*)(bp + (i64)((g0+c)*5+s)*512);
            acc[c][s] = __builtin_amdgcn_mfma_f32_16x16x32_bf16(a, bb, acc[c][s], 0, 0, 0);
          }
      }
      #pragma unroll
      for (int c=0;c<2;c++){
        const int hcol = hhb*64 + (g0+c)*16 + (lane&15);
        const float bi = b_iou[hcol], bo = b_iou[256+hcol], bu = b_iou[512+hcol];
        const float bfl = U_f_b[hcol], bfr2 = U_f_b[256+hcol];
        #pragma unroll
        for (int r=0;r<4;r++){
          const int row = mf*16 + qq*4 + r;
          if (row < M){
            const int cxor = (hcol*2) ^ ((row&7)<<4);
            const float cl = bf2f(*(const unsigned short*)(inC + row*1024 + cxor));
            const float cr = bf2f(*(const unsigned short*)(inC + row*1024 + 512 + cxor));
            const float i_ = acc[c][0][r]+bi, o_ = acc[c][1][r]+bo, u_ = acc[c][2][r]+bu;
            const float fl = acc[c][3][r]+bfl, fr = acc[c][4][r]+bfr2;
            const float cn = sigm(i_)*ftanh(u_) + sigm(fl)*cl + sigm(fr)*cr;
            const float hv = sigm(o_)*ftanh(cn);
            const int woff = row*512 + ((hcol*2) ^ (((row>>1)&7)<<4));
            *(short*)(outH + woff) = f2bf(hv);
            *(short*)(outC + woff) = f2bf(cn);
            hOut[(tb + s0v + row)*Hd + hcol] = hv;
            if (d == 0){
              outRoot[b*Hd + hcol] = hv;
              outRoot[Bb*Hd + b*Hd + hcol] = cn;
            }
          }
        }
      }
    }
    __syncthreads();
    char* t;
    t = inH; inH = outH; outH = t;
    t = inC; inC = outC; outC = t;
  }
}

extern "C" void kernel_launch(void* const* d_in, const int* in_sizes, int n_in,
                              void* d_out, int out_size, void* d_ws, size_t ws_size,
                              hipStream_t stream){
  const int*   wordid = (const int*)  d_in[0];
  const float* emb    = (const float*)d_in[6];
  const float* W_iou  = (const float*)d_in[7];
  const float* U_iou  = (const float*)d_in[8];
  const float* b_iou  = (const float*)d_in[9];
  const float* U_f_w  = (const float*)d_in[10];
  const float* U_f_b  = (const float*)d_in[11];

  float* hOut    = (float*)d_out;            // (B,T,H) fp32
  float* outRoot = hOut + NTH;               // root_h then root_c
  short* cbb  = (short*)d_ws;                // c bf16; root rows hold wemb overlay
  short* hb   = cbb + NTH;                   // h bf16; internal rows hold wemb overlay pre-leaf
  short* Wt2I = hb + NTH;                    // 655360 shorts
  short* Wt2L = Wt2I + 655360;               // 196608 shorts

  hipLaunchKernelGGL(prep_kernel, dim3(8608), dim3(256), 0, stream,
                     W_iou, U_iou, U_f_w, Wt2I, Wt2L, wordid, emb, hb, cbb);
  hipLaunchKernelGGL(leaf_gemm, dim3(4096), dim3(512), 0, stream,
                     hb, cbb, Wt2L, b_iou, hOut, hb, cbb);
  for (int d = 9; d >= 6; --d){
    const int s = (1<<d)-1, e = (2<<d)-1;
    hipLaunchKernelGGL(level_gemm, dim3(4<<d), dim3(512), 0, stream,
                       Wt2I, b_iou, U_f_b, hOut, hb, cbb, s, e, d);
  }
  hipLaunchKernelGGL(tree_fused, dim3(64), dim3(512), 0, stream,
                     Wt2I, b_iou, U_f_b, hOut, hb, cbb, outRoot);
}

// Round 25
// 336.509 us; speedup vs baseline: 1.9412x; 1.0396x over previous
//
#include <hip/hip_runtime.h>
#include <math.h>

typedef long long i64;
typedef short short8v __attribute__((ext_vector_type(8)));
typedef float float4v __attribute__((ext_vector_type(4)));

#define Hd 256
#define Bb 64
#define Tn 2047
#define LEAF0 1023
#define NTH 33538048LL   // B*T*H elements

__device__ __forceinline__ float frcp(float x){ return __builtin_amdgcn_rcpf(x); }
__device__ __forceinline__ float sigm(float x){ return frcp(1.0f+__expf(-x)); }
__device__ __forceinline__ float ftanh(float x){ return 1.0f - 2.0f*frcp(__expf(2.0f*x)+1.0f); }
__device__ __forceinline__ float bf2f(unsigned short s){
  union { unsigned u; float f; } v; v.u = ((unsigned)s)<<16; return v.f; }
__device__ __forceinline__ short f2bf(float f){
  union { float f; unsigned u; } v; v.f = f;
  unsigned r = v.u + 0x7FFF + ((v.u>>16)&1);
  return (short)(r>>16); }

#define GL2LDS(gp, lp) __builtin_amdgcn_global_load_lds( \
  (const __attribute__((address_space(1))) void*)(gp), \
  (__attribute__((address_space(3))) void*)(lp), 16, 0, 0)

// ---------------------------------------------------------------------------
// prep (R24 verbatim)
// ---------------------------------------------------------------------------
__global__ __launch_bounds__(256)
void prep_kernel(const float* __restrict__ W_iou, const float* __restrict__ U_iou,
                 const float* __restrict__ U_f_w,
                 short* __restrict__ Wt2I, short* __restrict__ Wt2L,
                 const int* __restrict__ wordid, const float* __restrict__ emb,
                 short* __restrict__ hb, short* __restrict__ cbb){
  if (blockIdx.x < 320){
    int t = blockIdx.x*256 + threadIdx.x;
    int lane = t & 63, rest = t >> 6;
    int nr = rest % 20; int rest2 = rest / 20;
    int kt = rest2 & 15, hhb = rest2 >> 4;
    int g = nr/5, strip = nr - g*5;
    int j = strip*256 + hhb*64 + g*16 + (lane&15);
    int k0 = kt*32 + (lane>>4)*8;
    const float* src = (j < 768) ? (U_iou + (i64)j*512 + k0)
                                 : (U_f_w + (i64)(j-768)*512 + k0);
    short* dst = Wt2I + (i64)t*8;
    #pragma unroll
    for (int e=0;e<8;e++) dst[e] = f2bf(src[e]);
  } else if (blockIdx.x < 416){
    int t2 = (blockIdx.x-320)*256 + threadIdx.x;
    int lane = t2 & 63, rest = t2 >> 6;
    int nr = rest % 12; int rest2 = rest / 12;
    int kt = rest2 & 7, hhb = rest2 >> 3;
    int g = nr/3, strip = nr - g*3;
    int j = strip*256 + hhb*64 + g*16 + (lane&15);
    int k0 = kt*32 + (lane>>4)*8;
    const float* src = W_iou + (i64)j*256 + k0;
    short* dst = Wt2L + (i64)t2*8;
    #pragma unroll
    for (int e=0;e<8;e++) dst[e] = f2bf(src[e]);
  } else {
    int id = (blockIdx.x-416)*256 + threadIdx.x;
    int row = id >> 5, q = id & 31;
    int b = row >> 10, j = row & 1023;
    i64 tb = (i64)b*Tn;
    const int* wid = wordid + (tb + LEAF0 + j)*5;
    float s[8];
    #pragma unroll
    for (int e=0;e<8;e++) s[e] = 0.f;
    #pragma unroll
    for (int l=0;l<5;l++){
      const float* er = emb + (i64)wid[l]*Hd + q*8;
      float4 v0 = *(const float4*)(er);
      float4 v1 = *(const float4*)(er+4);
      s[0]+=v0.x; s[1]+=v0.y; s[2]+=v0.z; s[3]+=v0.w;
      s[4]+=v1.x; s[5]+=v1.y; s[6]+=v1.z; s[7]+=v1.w;
    }
    short o[8];
    #pragma unroll
    for (int e=0;e<8;e++) o[e] = f2bf(s[e]);
    short* dst = (j < 1023) ? (hb + (tb + j)*Hd) : (cbb + tb*Hd);
    *(short8v*)(dst + q*8) = *(short8v*)o;
  }
}

// ---------------------------------------------------------------------------
// Leaf GEMM (R24 verbatim, no c0 read)
// ---------------------------------------------------------------------------
#define LEAF_IT(I, V1, V2)                                                   \
  {                                                                          \
    _Pragma("unroll")                                                        \
    for (int st=0; st<3; ++st)                                               \
      qb[st] = *(const short8v*)(wbB + (i64)((I)*2+1)*12*512 + (i64)st*512); \
    asm volatile("" ::: "memory");                                           \
    if ((I)+2 < 4) GL2LDS(srcA + ((I)+2)*64, &As[(((I)+2)&3)*4096 + w*512]); \
    asm volatile("" ::: "memory");                                           \
    asm volatile("s_waitcnt vmcnt(" #V1 ")" ::: "memory");                   \
    __builtin_amdgcn_s_barrier();                                            \
    asm volatile("" ::: "memory");                                           \
    {                                                                        \
      short8v a0 = *(const short8v*)&As[((I)&3)*4096 + (wm*2+0)*512 + lane*8]; \
      short8v a1 = *(const short8v*)&As[((I)&3)*4096 + (wm*2+1)*512 + lane*8]; \
      _Pragma("unroll")                                                      \
      for (int st=0; st<3; ++st){                                            \
        acc[0][st] = __builtin_amdgcn_mfma_f32_16x16x32_bf16(a0, pb[st], acc[0][st], 0,0,0); \
        acc[1][st] = __builtin_amdgcn_mfma_f32_16x16x32_bf16(a1, pb[st], acc[1][st], 0,0,0); \
      }                                                                      \
    }                                                                        \
    asm volatile("" ::: "memory");                                           \
    if ((I)+1 < 4){                                                          \
      _Pragma("unroll")                                                      \
      for (int st=0; st<3; ++st)                                             \
        pb[st] = *(const short8v*)(wbB + (i64)((I)+1)*2*12*512 + (i64)st*512); \
    }                                                                        \
    asm volatile("" ::: "memory");                                           \
    asm volatile("s_waitcnt vmcnt(" #V2 ")" ::: "memory");                   \
    {                                                                        \
      short8v a0 = *(const short8v*)&As[((I)&3)*4096 + 2048 + (wm*2+0)*512 + lane*8]; \
      short8v a1 = *(const short8v*)&As[((I)&3)*4096 + 2048 + (wm*2+1)*512 + lane*8]; \
      _Pragma("unroll")                                                      \
      for (int st=0; st<3; ++st){                                            \
        acc[0][st] = __builtin_amdgcn_mfma_f32_16x16x32_bf16(a0, qb[st], acc[0][st], 0,0,0); \
        acc[1][st] = __builtin_amdgcn_mfma_f32_16x16x32_bf16(a1, qb[st], acc[1][st], 0,0,0); \
      }                                                                      \
    }                                                                        \
    asm volatile("s_waitcnt lgkmcnt(0)" ::: "memory");                       \
  }

__global__ __launch_bounds__(512, 4)
void leaf_gemm(const short* __restrict__ hb, const short* __restrict__ cbb,
               const short* __restrict__ WB,
               const float* __restrict__ b_iou,
               float* __restrict__ hOut, short* __restrict__ hbOut,
               short* __restrict__ cbbOut){
  __shared__ __align__(16) short As[4*4096];   // 32 KB ring-4
  const int tid = threadIdx.x;
  const int lane = tid & 63, w = tid >> 6;
  const int wm = w >> 2, wg = w & 3;           // output role
  const int bid = blockIdx.x;
  const int hhb = bid & 3;
  const int m0 = (bid >> 2) * 64;

  const short* srcA;                            // staging role: rg=w&3, sub=w>>2
  {
    const int r = m0 + (w&3)*16 + (lane&15);
    const int bA = r >> 10, jA = r & 1023;
    srcA = ((jA < 1023) ? (hb + ((i64)bA*Tn + jA)*Hd) : (cbb + (i64)bA*Tn*Hd))
           + (w>>2)*32 + (lane>>4)*8;
  }
  const short* wbB = WB + (i64)hhb*96*512 + (i64)(wg*3)*512 + lane*8;

  float4v acc[2][3];
  #pragma unroll
  for (int mr=0;mr<2;mr++)
    #pragma unroll
    for (int st=0;st<3;st++){ float4v z = {0.f,0.f,0.f,0.f}; acc[mr][st] = z; }

  short8v pb[3], qb[3];
  #pragma unroll
  for (int st=0; st<3; ++st) pb[st] = *(const short8v*)(wbB + (i64)st*512);
  asm volatile("" ::: "memory");
  GL2LDS(srcA,      &As[0*4096 + w*512]);
  GL2LDS(srcA + 64, &As[1*4096 + w*512]);
  asm volatile("" ::: "memory");

  LEAF_IT(0,5,4)  LEAF_IT(1,4,4)  LEAF_IT(2,3,3)  LEAF_IT(3,3,0)

  const int hcol = hhb*64 + wg*16 + (lane&15);
  const float bi = b_iou[hcol], bo = b_iou[256+hcol], bu = b_iou[512+hcol];
  #pragma unroll
  for (int mr=0;mr<2;mr++){
    const int mgb = m0 + wm*32 + mr*16 + ((lane>>4)<<2);
    #pragma unroll
    for (int r=0;r<4;r++){
      const int m = mgb + r;
      const int b = m >> 10, j = m & 1023;
      const i64 n = (i64)b*Tn + LEAF0 + j;
      const float i_ = acc[mr][0][r] + bi;
      const float o_ = acc[mr][1][r] + bo;
      const float u_ = acc[mr][2][r] + bu;
      const float cn = sigm(i_)*ftanh(u_);            // c0 == 0 for this problem
      const float hv = sigm(o_)*ftanh(cn);
      cbbOut[n*Hd + hcol] = f2bf(cn);
      hbOut[n*Hd + hcol]  = f2bf(hv);
      hOut[n*Hd + hcol] = hv;
    }
  }
}

// ---------------------------------------------------------------------------
// Internal level d=9..6 (R24 verbatim)
// ---------------------------------------------------------------------------
#define LVL_IT(I, V1, V2)                                                    \
  {                                                                          \
    _Pragma("unroll")                                                        \
    for (int st=0; st<5; ++st)                                               \
      qb[st] = *(const short8v*)(wbB + (i64)((I)*2+1)*20*512 + (i64)st*512); \
    asm volatile("" ::: "memory");                                           \
    if ((I)+2 < 8) GL2LDS(srcA + ((I)+2)*64, &As[(((I)+2)&3)*4096 + w*512]); \
    asm volatile("" ::: "memory");                                           \
    asm volatile("s_waitcnt vmcnt(" #V1 ")" ::: "memory");                   \
    __builtin_amdgcn_s_barrier();                                            \
    asm volatile("" ::: "memory");                                           \
    {                                                                        \
      short8v a0 = *(const short8v*)&As[((I)&3)*4096 + (wm*2+0)*512 + lane*8]; \
      short8v a1 = *(const short8v*)&As[((I)&3)*4096 + (wm*2+1)*512 + lane*8]; \
      _Pragma("unroll")                                                      \
      for (int st=0; st<5; ++st){                                            \
        acc[0][st] = __builtin_amdgcn_mfma_f32_16x16x32_bf16(a0, pb[st], acc[0][st], 0,0,0); \
        acc[1][st] = __builtin_amdgcn_mfma_f32_16x16x32_bf16(a1, pb[st], acc[1][st], 0,0,0); \
      }                                                                      \
    }                                                                        \
    asm volatile("" ::: "memory");                                           \
    if ((I)+1 < 8){                                                          \
      _Pragma("unroll")                                                      \
      for (int st=0; st<5; ++st)                                             \
        pb[st] = *(const short8v*)(wbB + (i64)((I)+1)*2*20*512 + (i64)st*512); \
    }                                                                        \
    asm volatile("" ::: "memory");                                           \
    asm volatile("s_waitcnt vmcnt(" #V2 ")" ::: "memory");                   \
    {                                                                        \
      short8v a0 = *(const short8v*)&As[((I)&3)*4096 + 2048 + (wm*2+0)*512 + lane*8]; \
      short8v a1 = *(const short8v*)&As[((I)&3)*4096 + 2048 + (wm*2+1)*512 + lane*8]; \
      _Pragma("unroll")                                                      \
      for (int st=0; st<5; ++st){                                            \
        acc[0][st] = __builtin_amdgcn_mfma_f32_16x16x32_bf16(a0, qb[st], acc[0][st], 0,0,0); \
        acc[1][st] = __builtin_amdgcn_mfma_f32_16x16x32_bf16(a1, qb[st], acc[1][st], 0,0,0); \
      }                                                                      \
    }                                                                        \
    asm volatile("s_waitcnt lgkmcnt(0)" ::: "memory");                       \
  }

__global__ __launch_bounds__(512, 4)
void level_gemm(const short* __restrict__ WB,
                const float* __restrict__ b_iou, const float* __restrict__ U_f_b,
                float* __restrict__ hOut, short* __restrict__ hb, short* __restrict__ cbb,
                int s0, int e0, int logn){
  __shared__ __align__(16) short As[4*4096];   // 32 KB ring-4
  const int tid = threadIdx.x;
  const int lane = tid & 63, w = tid >> 6;
  const int wm = w >> 2, wg = w & 3;
  const int bid = blockIdx.x;
  const int hhb = bid & 3;
  const int m0 = (bid >> 2) * 64;
  const int nm1 = (1<<logn)-1;

  const short* srcA;
  {
    const int r = m0 + (w&3)*16 + (lane&15);
    const int bA = r >> logn, jA = r & nm1;
    srcA = hb + ((i64)bA*Tn + e0)*Hd + (i64)jA*512 + (w>>2)*32 + (lane>>4)*8;
  }
  const short* wbB = WB + (i64)hhb*320*512 + (i64)(wg*5)*512 + lane*8;

  float4v acc[2][5];
  #pragma unroll
  for (int mr=0;mr<2;mr++)
    #pragma unroll
    for (int st=0;st<5;st++){ float4v z = {0.f,0.f,0.f,0.f}; acc[mr][st] = z; }

  short8v pb[5], qb[5];
  #pragma unroll
  for (int st=0; st<5; ++st) pb[st] = *(const short8v*)(wbB + (i64)st*512);
  asm volatile("" ::: "memory");
  GL2LDS(srcA,      &As[0*4096 + w*512]);
  GL2LDS(srcA + 64, &As[1*4096 + w*512]);
  asm volatile("" ::: "memory");

  LVL_IT(0,7,6)  LVL_IT(1,6,6)  LVL_IT(2,6,6)  LVL_IT(3,6,6)
  LVL_IT(4,6,6)  LVL_IT(5,6,6)  LVL_IT(6,5,5)  LVL_IT(7,5,0)

  const int hcol = hhb*64 + wg*16 + (lane&15);
  const float bi = b_iou[hcol], bo = b_iou[256+hcol], bu = b_iou[512+hcol];
  const float bfl = U_f_b[hcol], bfr2 = U_f_b[256+hcol];
  #pragma unroll
  for (int mr=0;mr<2;mr++){
    const int mgb = m0 + wm*32 + mr*16 + ((lane>>4)<<2);
    #pragma unroll
    for (int r=0;r<4;r++){
      const int m = mgb + r;
      const int b = m >> logn, j = m & nm1;
      const i64 base = (i64)b*Tn;
      const i64 cidx = (base + e0 + 2*j)*Hd + hcol;
      const float cl = bf2f((unsigned short)cbb[cidx]);
      const float cr = bf2f((unsigned short)cbb[cidx + Hd]);
      const float i_ = acc[mr][0][r]+bi, o_ = acc[mr][1][r]+bo, u_ = acc[mr][2][r]+bu;
      const float fl = acc[mr][3][r]+bfl, fr = acc[mr][4][r]+bfr2;
      const float cn = sigm(i_)*ftanh(u_) + sigm(fl)*cl + sigm(fr)*cr;
      const float hv = sigm(o_)*ftanh(cn);
      const i64 oidx = (base + s0 + j)*Hd + hcol;
      cbb[oidx] = f2bf(cn);
      hb[oidx]  = f2bf(hv);
      hOut[oidx] = hv;
    }
  }
}

// ---------------------------------------------------------------------------
// Fused small levels d=5..0 v4: 1024 threads = 16 waves; wave = 1 colgroup
// (hhb = w>>2, g = w&3) x 5 strips — per-wave load chain halved, 4 waves/SIMD.
// Children h/c ping-pong in XOR-swizzled LDS; B from L2; 1 barrier/level.
// ---------------------------------------------------------------------------
__global__ __launch_bounds__(1024)
void tree_fused(const short* __restrict__ WB, const float* __restrict__ b_iou,
                const float* __restrict__ U_f_b, float* __restrict__ hOut,
                const short* __restrict__ hb, const short* __restrict__ cbb,
                float* __restrict__ outRoot){
  __shared__ __align__(16) char BUF[96*1024];
  char* bAh = BUF;
  char* bAc = BUF + 32*1024;
  char* bBh = BUF + 64*1024;
  char* bBc = BUF + 80*1024;
  const int tid = threadIdx.x;
  const int lane = tid & 63, w = tid >> 6;
  const int hhb = w >> 2;        // 0..3
  const int g   = w & 3;         // colgroup 0..3
  const int b = blockIdx.x;
  const i64 tb = (i64)b*Tn;

  // stage level-6 children: tree rows 63..126 (64 rows) of h and c
  #pragma unroll
  for (int p=0;p<2;p++){
    int idx = p*1024 + tid;
    int row = idx >> 5, ch = idx & 31;
    int off = row*512 + ((ch*16) ^ (((row>>1)&7)<<4));
    *(short8v*)(bAh + off) = *(const short8v*)(hb  + (tb + 63 + row)*Hd + ch*8);
    *(short8v*)(bAc + off) = *(const short8v*)(cbb + (tb + 63 + row)*Hd + ch*8);
  }
  __syncthreads();

  char* inH = bAh; char* inC = bAc; char* outH = bBh; char* outC = bBc;

  for (int d = 5; d >= 0; --d){
    const int M = 1<<d, s0v = M-1;
    const int nmf = (d == 5) ? 2 : 1;
    for (int mf = 0; mf < nmf; ++mf){
      const int j = mf*16 + (lane&15);
      const int qq = lane >> 4;
      float4v acc[5];
      #pragma unroll
      for (int s=0;s<5;s++){ float4v z = {0.f,0.f,0.f,0.f}; acc[s] = z; }
      #pragma unroll 4
      for (int kt=0; kt<16; ++kt){
        const int crow = 2*j + (kt>>3);
        const int ccolB = ((kt&7)*32 + qq*8)*2;
        short8v a = *(const short8v*)(inH + crow*512 + (ccolB ^ (((crow>>1)&7)<<4)));
        const short* bp = WB + (i64)hhb*163840 + (i64)kt*10240 + (i64)lane*8;
        #pragma unroll
        for (int s=0;s<5;s++){
          short8v bb = *(const short8v*)(bp + (i64)(g*5+s)*512);
          acc[s] = __builtin_amdgcn_mfma_f32_16x16x32_bf16(a, bb, acc[s], 0, 0, 0);
        }
      }
      {
        const int hcol = hhb*64 + g*16 + (lane&15);
        const float bi = b_iou[hcol], bo = b_iou[256+hcol], bu = b_iou[512+hcol];
        const float bfl = U_f_b[hcol], bfr2 = U_f_b[256+hcol];
        #pragma unroll
        for (int r=0;r<4;r++){
          const int row = mf*16 + qq*4 + r;
          if (row < M){
            const int cxor = (hcol*2) ^ ((row&7)<<4);
            const float cl = bf2f(*(const unsigned short*)(inC + row*1024 + cxor));
            const float cr = bf2f(*(const unsigned short*)(inC + row*1024 + 512 + cxor));
            const float i_ = acc[0][r]+bi, o_ = acc[1][r]+bo, u_ = acc[2][r]+bu;
            const float fl = acc[3][r]+bfl, fr = acc[4][r]+bfr2;
            const float cn = sigm(i_)*ftanh(u_) + sigm(fl)*cl + sigm(fr)*cr;
            const float hv = sigm(o_)*ftanh(cn);
            const int woff = row*512 + ((hcol*2) ^ (((row>>1)&7)<<4));
            *(short*)(outH + woff) = f2bf(hv);
            *(short*)(outC + woff) = f2bf(cn);
            hOut[(tb + s0v + row)*Hd + hcol] = hv;
            if (d == 0){
              outRoot[b*Hd + hcol] = hv;
              outRoot[Bb*Hd + b*Hd + hcol] = cn;
            }
          }
        }
      }
    }
    __syncthreads();
    char* t;
    t = inH; inH = outH; outH = t;
    t = inC; inC = outC; outC = t;
  }
}

extern "C" void kernel_launch(void* const* d_in, const int* in_sizes, int n_in,
                              void* d_out, int out_size, void* d_ws, size_t ws_size,
                              hipStream_t stream){
  const int*   wordid = (const int*)  d_in[0];
  const float* emb    = (const float*)d_in[6];
  const float* W_iou  = (const float*)d_in[7];
  const float* U_iou  = (const float*)d_in[8];
  const float* b_iou  = (const float*)d_in[9];
  const float* U_f_w  = (const float*)d_in[10];
  const float* U_f_b  = (const float*)d_in[11];

  float* hOut    = (float*)d_out;            // (B,T,H) fp32
  float* outRoot = hOut + NTH;               // root_h then root_c
  short* cbb  = (short*)d_ws;                // c bf16; root rows hold wemb overlay
  short* hb   = cbb + NTH;                   // h bf16; internal rows hold wemb overlay pre-leaf
  short* Wt2I = hb + NTH;                    // 655360 shorts
  short* Wt2L = Wt2I + 655360;               // 196608 shorts

  hipLaunchKernelGGL(prep_kernel, dim3(8608), dim3(256), 0, stream,
                     W_iou, U_iou, U_f_w, Wt2I, Wt2L, wordid, emb, hb, cbb);
  hipLaunchKernelGGL(leaf_gemm, dim3(4096), dim3(512), 0, stream,
                     hb, cbb, Wt2L, b_iou, hOut, hb, cbb);
  for (int d = 9; d >= 6; --d){
    const int s = (1<<d)-1, e = (2<<d)-1;
    hipLaunchKernelGGL(level_gemm, dim3(4<<d), dim3(512), 0, stream,
                       Wt2I, b_iou, U_f_b, hOut, hb, cbb, s, e, d);
  }
  hipLaunchKernelGGL(tree_fused, dim3(64), dim3(1024), 0, stream,
                     Wt2I, b_iou, U_f_b, hOut, hb, cbb, outRoot);
}